// Round 2
// baseline (619.836 us; speedup 1.0000x reference)
//
#include <hip/hip_runtime.h>
#include <hip/hip_bf16.h>

typedef __attribute__((ext_vector_type(8))) short bf16x8;
typedef __attribute__((ext_vector_type(4))) float f32x4;

static __device__ __forceinline__ unsigned short f2bf(float f) {
    unsigned int u = __float_as_uint(f);
    u = u + 0x7FFFu + ((u >> 16) & 1u);   // RNE; inputs are finite
    return (unsigned short)(u >> 16);
}

static __device__ __forceinline__ float fast_tanh(float x) {
    x = fminf(fmaxf(x, -10.f), 10.f);
    float e = __expf(2.f * x);
    return __fdividef(e - 1.f, e + 1.f);
}

// ---------------- generic small fp32 GEMM: C[m][n] = sum_k A[m][k]*W[n*ldw+woff+k] + bias[n]
__global__ __launch_bounds__(256)
void sgemm_bt(const float* __restrict__ A, const float* __restrict__ W,
              const float* __restrict__ bias, float* __restrict__ C,
              int N, int K, int ldw, int woff)
{
    __shared__ float As[64][33];
    __shared__ float Ws[64][33];
    const int tid = threadIdx.x;
    const int tx = tid & 15, ty = tid >> 4;
    const int m0 = blockIdx.x * 64, n0 = blockIdx.y * 64;
    const int kc = tid & 31;
    const int r0 = tid >> 5;
    float acc[4][4] = {};
    for (int k0 = 0; k0 < K; k0 += 32) {
        #pragma unroll
        for (int i = 0; i < 8; ++i) {
            int row = r0 + i * 8;
            As[row][kc] = A[(m0 + row) * K + k0 + kc];
            int n = n0 + row;
            Ws[row][kc] = (n < N) ? W[(long)n * ldw + woff + k0 + kc] : 0.f;
        }
        __syncthreads();
        #pragma unroll
        for (int kk = 0; kk < 32; ++kk) {
            float a[4], w[4];
            #pragma unroll
            for (int i = 0; i < 4; ++i) a[i] = As[ty * 4 + i][kk];
            #pragma unroll
            for (int j = 0; j < 4; ++j) w[j] = Ws[tx * 4 + j][kk];
            #pragma unroll
            for (int i = 0; i < 4; ++i)
                #pragma unroll
                for (int j = 0; j < 4; ++j) acc[i][j] += a[i] * w[j];
        }
        __syncthreads();
    }
    #pragma unroll
    for (int i = 0; i < 4; ++i) {
        int m = m0 + ty * 4 + i;
        #pragma unroll
        for (int j = 0; j < 4; ++j) {
            int n = n0 + tx * 4 + j;
            if (n < N) C[m * N + n] = acc[i][j] + (bias ? bias[n] : 0.f);
        }
    }
}

// ---------------- attention: one block per (row n, head h). 8 heads, HEAD_D=32.
__global__ __launch_bounds__(256)
void attn_kernel(const float* __restrict__ qkv, float* __restrict__ out)
{
    const int n = blockIdx.x;
    const int h = blockIdx.y;
    const int tid = threadIdx.x;
    const int lane = tid & 63;
    const int wid = tid >> 6;

    __shared__ float qs[32];
    __shared__ float p[384];
    __shared__ float red[8];
    __shared__ float pv[8][32];

    if (tid < 32) qs[tid] = qkv[n * 768 + h * 32 + tid] * 0.17677669529663687f; // /sqrt(32)
    __syncthreads();

    float lmax = -1e30f;
    for (int m = tid; m < 384; m += 256) {
        const float4* kr = (const float4*)(qkv + m * 768 + 256 + h * 32);
        float s = 0.f;
        #pragma unroll
        for (int d = 0; d < 8; ++d) {
            float4 kv = kr[d];
            s += qs[d*4+0]*kv.x + qs[d*4+1]*kv.y + qs[d*4+2]*kv.z + qs[d*4+3]*kv.w;
        }
        p[m] = s;
        lmax = fmaxf(lmax, s);
    }
    #pragma unroll
    for (int off = 32; off >= 1; off >>= 1) lmax = fmaxf(lmax, __shfl_xor(lmax, off));
    if (lane == 0) red[wid] = lmax;
    __syncthreads();
    const float gmax = fmaxf(fmaxf(red[0], red[1]), fmaxf(red[2], red[3]));

    float lsum = 0.f;
    for (int m = tid; m < 384; m += 256) {
        float e = __expf(p[m] - gmax);
        p[m] = e;
        lsum += e;
    }
    #pragma unroll
    for (int off = 32; off >= 1; off >>= 1) lsum += __shfl_xor(lsum, off);
    if (lane == 0) red[4 + wid] = lsum;
    __syncthreads();
    const float inv = 1.f / (red[4] + red[5] + red[6] + red[7]);

    const int d = tid & 31;
    const int g = tid >> 5;
    float acc = 0.f;
    for (int m = g * 48; m < g * 48 + 48; ++m)
        acc += p[m] * qkv[m * 768 + 512 + h * 32 + d];
    pv[g][d] = acc;
    __syncthreads();
    if (tid < 32) {
        float o = 0.f;
        #pragma unroll
        for (int gg = 0; gg < 8; ++gg) o += pv[gg][tid];
        out[n * 256 + h * 32 + tid] = o * inv;
    }
}

// ---------------- fused tail: hA / hBv / node(+scatter) GEMMs + fci_w2->bf16.
// grid (6, 11), 256 threads. y<4: hA, y<8: hBv, y<10: node->scatter, y==10: w2 conv.
__global__ __launch_bounds__(256)
void fused_tail(const float* __restrict__ h2,
                const float* __restrict__ fci_w1, const float* __restrict__ fci_b1,
                const float* __restrict__ fcn_w,  const float* __restrict__ fcn_b,
                const float* __restrict__ fci_w2,
                float* __restrict__ hA, float* __restrict__ hBv,
                unsigned short* __restrict__ w2b, float* __restrict__ out)
{
    const int y = blockIdx.y;
    const int tid = threadIdx.x;
    if (y == 10) {
        for (int i = blockIdx.x * 256 + tid; i < 204800; i += 1536)
            w2b[i] = f2bf(fci_w2[i]);
        return;
    }
    const float* W    = (y < 8) ? fci_w1 : fcn_w;
    const float* bias = (y < 4) ? fci_b1 : ((y < 8) ? nullptr : fcn_b);
    const int ldw  = (y < 8) ? 512 : 256;
    const int woff = (y >= 4 && y < 8) ? 256 : 0;
    const int n0   = (y < 4) ? y * 64 : ((y < 8) ? (y - 4) * 64 : (y - 8) * 64);
    const int NN   = (y < 8) ? 256 : 80;

    __shared__ float As[64][33];
    __shared__ float Ws[64][33];
    const int tx = tid & 15, ty = tid >> 4;
    const int m0 = blockIdx.x * 64;
    const int kc = tid & 31;
    const int r0 = tid >> 5;
    float acc[4][4] = {};
    for (int k0 = 0; k0 < 256; k0 += 32) {
        #pragma unroll
        for (int i = 0; i < 8; ++i) {
            int row = r0 + i * 8;
            As[row][kc] = h2[(m0 + row) * 256 + k0 + kc];
            int n = n0 + row;
            Ws[row][kc] = (n < NN) ? W[(long)n * ldw + woff + k0 + kc] : 0.f;
        }
        __syncthreads();
        #pragma unroll
        for (int kk = 0; kk < 32; ++kk) {
            float a[4], w[4];
            #pragma unroll
            for (int i = 0; i < 4; ++i) a[i] = As[ty * 4 + i][kk];
            #pragma unroll
            for (int j = 0; j < 4; ++j) w[j] = Ws[tx * 4 + j][kk];
            #pragma unroll
            for (int i = 0; i < 4; ++i)
                #pragma unroll
                for (int j = 0; j < 4; ++j) acc[i][j] += a[i] * w[j];
        }
        __syncthreads();
    }
    if (y < 8) {
        float* C = (y < 4) ? hA : hBv;
        #pragma unroll
        for (int i = 0; i < 4; ++i) {
            int m = m0 + ty * 4 + i;
            #pragma unroll
            for (int j = 0; j < 4; ++j) {
                int n = n0 + tx * 4 + j;
                C[m * 256 + n] = acc[i][j] + (bias ? bias[n] : 0.f);
            }
        }
    } else {
        #pragma unroll
        for (int i = 0; i < 4; ++i) {
            int m = m0 + ty * 4 + i;
            #pragma unroll
            for (int j = 0; j < 4; ++j) {
                int c = n0 + tx * 4 + j;
                if (c < 80) {
                    float v = acc[i][j] + fcn_b[c];
                    if (c < 64)      out[117964800 + m * 64 + c] = v;
                    else if (c < 72) out[117989376 + m * 8 + (c - 64)] = v;
                    else             out[117992448 + m * 8 + (c - 72)] = v;
                }
            }
        }
    }
}

// ---------------- the big fused kernel, v2.
// Per block: 128 rows of T = tanh(hA[j]+hB[ai]) built ONCE into register A-fragments;
// loop 5 ntiles of 160 w2-rows staged in 80KB LDS (2 blocks/CU); swapped-operand MFMA
// gives 4 consecutive output cols per lane -> float4 stores.
#define GBM 128

__global__ __launch_bounds__(512, 4)
void gen_kq(const float* __restrict__ hA, const float* __restrict__ hB,
            const unsigned short* __restrict__ w2b, const float* __restrict__ b2,
            float* __restrict__ outK, float* __restrict__ outQ)
{
    __shared__ unsigned char Bs[160 * 512];   // 80 KB: 160 rows x 256 bf16, XOR-swizzled

    const int tid  = threadIdx.x;
    const int lane = tid & 63;
    const int wid  = tid >> 6;      // 8 waves: 4(M) x 2(N)
    const int wm   = wid >> 1;
    const int wn   = wid & 1;
    const int lr   = lane & 15;
    const int kg   = lane >> 4;

    const int m0  = blockIdx.x * GBM;
    const int ai  = m0 / 384;           // constant per block (384 = 3*128)
    const int bj0 = m0 - ai * 384;

    // ---- issue B(t=0) prefetch
    const int kc  = tid & 31;           // k-chunk of 8 bf16
    const int rB0 = tid >> 5;           // 0..15
    uint4 breg[10];
    #pragma unroll
    for (int it = 0; it < 10; ++it)
        breg[it] = *(const uint4*)(w2b + (size_t)(rB0 + it * 16) * 256 + kc * 8);

    // ---- build A fragments in registers (tanh once per block); hides B-load latency
    bf16x8 af[2][8];
    {
        const int row0 = bj0 + wm * 32 + lr;
        #pragma unroll
        for (int kk = 0; kk < 8; ++kk) {
            const int ke = kk * 32 + kg * 8;
            const float4 b0 = *(const float4*)(hB + ai * 256 + ke);
            const float4 b1 = *(const float4*)(hB + ai * 256 + ke + 4);
            #pragma unroll
            for (int i = 0; i < 2; ++i) {
                const float4* pa = (const float4*)(hA + (row0 + i * 16) * 256 + ke);
                const float4 a0 = pa[0], a1 = pa[1];
                bf16x8 v;
                v[0] = (short)f2bf(fast_tanh(a0.x + b0.x));
                v[1] = (short)f2bf(fast_tanh(a0.y + b0.y));
                v[2] = (short)f2bf(fast_tanh(a0.z + b0.z));
                v[3] = (short)f2bf(fast_tanh(a0.w + b0.w));
                v[4] = (short)f2bf(fast_tanh(a1.x + b1.x));
                v[5] = (short)f2bf(fast_tanh(a1.y + b1.y));
                v[6] = (short)f2bf(fast_tanh(a1.z + b1.z));
                v[7] = (short)f2bf(fast_tanh(a1.w + b1.w));
                af[i][kk] = v;
            }
        }
    }

    // ---- write B(t=0) to LDS
    #pragma unroll
    for (int it = 0; it < 10; ++it) {
        const int r = rB0 + it * 16;
        *(uint4*)(Bs + (r << 9) + ((kc << 4) ^ ((r & 7) << 4))) = breg[it];
    }
    __syncthreads();

    #pragma unroll
    for (int t = 0; t < 5; ++t) {
        // prefetch next B tile into regs (overlaps MFMA below)
        if (t < 4) {
            #pragma unroll
            for (int it = 0; it < 10; ++it)
                breg[it] = *(const uint4*)(w2b + (size_t)((t + 1) * 160 + rB0 + it * 16) * 256 + kc * 8);
        }

        f32x4 acc[2][5];
        #pragma unroll
        for (int i = 0; i < 2; ++i)
            #pragma unroll
            for (int j = 0; j < 5; ++j)
                acc[i][j] = (f32x4){0.f, 0.f, 0.f, 0.f};

        #pragma unroll
        for (int kk = 0; kk < 8; ++kk) {
            const int kb = kk * 64 + (kg << 4);
            bf16x8 bfr[5];
            #pragma unroll
            for (int j = 0; j < 5; ++j) {
                const int r = wn * 80 + j * 16 + lr;
                bfr[j] = *(const bf16x8*)(Bs + (r << 9) + (kb ^ ((r & 7) << 4)));
            }
            #pragma unroll
            for (int i = 0; i < 2; ++i)
                #pragma unroll
                for (int j = 0; j < 5; ++j)
                    acc[i][j] = __builtin_amdgcn_mfma_f32_16x16x32_bf16(bfr[j], af[i][kk], acc[i][j], 0, 0, 0);
        }

        // epilogue: swapped layout -> lane&15 = m-offset, (lane>>4)*4+reg = n-offset
        #pragma unroll
        for (int j = 0; j < 5; ++j) {
            const int nb = t * 160 + wn * 80 + j * 16 + (kg << 2);
            const float4 bias = *(const float4*)(b2 + nb);
            float* base = (nb < 400) ? (outK + nb) : (outQ + (nb - 400));
            #pragma unroll
            for (int i = 0; i < 2; ++i) {
                const int m = m0 + wm * 32 + i * 16 + lr;
                float4 v;
                v.x = acc[i][j][0] + bias.x;
                v.y = acc[i][j][1] + bias.y;
                v.z = acc[i][j][2] + bias.z;
                v.w = acc[i][j][3] + bias.w;
                *(float4*)(base + (size_t)m * 400) = v;
            }
        }
        __syncthreads();           // all waves done reading Bs
        if (t < 4) {
            #pragma unroll
            for (int it = 0; it < 10; ++it) {
                const int r = rB0 + it * 16;
                *(uint4*)(Bs + (r << 9) + ((kc << 4) ^ ((r & 7) << 4))) = breg[it];
            }
            __syncthreads();
        }
    }
}

extern "C" void kernel_launch(void* const* d_in, const int* in_sizes, int n_in,
                              void* d_out, int out_size, void* d_ws, size_t ws_size,
                              hipStream_t stream)
{
    (void)in_sizes; (void)n_in; (void)out_size; (void)ws_size;

    const float* h      = (const float*)d_in[0];
    const float* fc_w   = (const float*)d_in[1];
    const float* fc_b   = (const float*)d_in[2];
    const float* inp_w  = (const float*)d_in[3];
    const float* inp_b  = (const float*)d_in[4];
    const float* outp_w = (const float*)d_in[5];
    const float* outp_b = (const float*)d_in[6];
    const float* fci_w1 = (const float*)d_in[7];
    const float* fci_b1 = (const float*)d_in[8];
    const float* fci_w2 = (const float*)d_in[9];
    const float* fci_b2 = (const float*)d_in[10];
    const float* fcn_w  = (const float*)d_in[11];
    const float* fcn_b  = (const float*)d_in[12];

    float* out  = (float*)d_out;
    float* outK = out;
    float* outQ = out + 58982400;   // 384*384*400

    float* ws   = (float*)d_ws;
    float* h1   = ws;                    // 384*256
    float* qkv  = h1   + 384 * 256;      // 384*768
    float* attn = qkv  + 384 * 768;      // 384*256
    float* h2   = attn + 384 * 256;      // 384*256
    float* hA   = h2   + 384 * 256;      // 384*256  (b1 folded in)
    float* hBv  = hA   + 384 * 256;      // 384*256
    float* node = hBv  + 384 * 256;      // 384*80 (reserved, keeps w2b alignment)
    unsigned short* w2b = (unsigned short*)(node + 384 * 80); // 800*256 bf16

    sgemm_bt<<<dim3(6, 4),  256, 0, stream>>>(h,    fc_w,   fc_b,   h1,   256, 128, 128, 0);
    sgemm_bt<<<dim3(6, 12), 256, 0, stream>>>(h1,   inp_w,  inp_b,  qkv,  768, 256, 256, 0);
    attn_kernel<<<dim3(384, 8), 256, 0, stream>>>(qkv, attn);
    sgemm_bt<<<dim3(6, 4),  256, 0, stream>>>(attn, outp_w, outp_b, h2,   256, 256, 256, 0);
    fused_tail<<<dim3(6, 11), 256, 0, stream>>>(h2, fci_w1, fci_b1, fcn_w, fcn_b, fci_w2,
                                                hA, hBv, w2b, out);
    gen_kq<<<dim3(1152), 512, 0, stream>>>(hA, hBv, w2b, fci_b2, outK, outQ);
}

// Round 3
// 414.907 us; speedup vs baseline: 1.4939x; 1.4939x over previous
//
#include <hip/hip_runtime.h>
#include <hip/hip_bf16.h>

typedef __attribute__((ext_vector_type(8))) short bf16x8;
typedef __attribute__((ext_vector_type(4))) float f32x4;

static __device__ __forceinline__ unsigned int f2bf(float f) {
    unsigned int u = __float_as_uint(f);
    u = u + 0x7FFFu + ((u >> 16) & 1u);   // RNE; inputs are finite
    return (u >> 16);
}

static __device__ __forceinline__ float fast_tanh(float x) {
    x = fminf(fmaxf(x, -10.f), 10.f);
    float e = __expf(2.f * x);
    return __fdividef(e - 1.f, e + 1.f);
}

// ---------------- generic small fp32 GEMM: C[m][n] = sum_k A[m][k]*W[n*ldw+woff+k] + bias[n]
__global__ __launch_bounds__(256)
void sgemm_bt(const float* __restrict__ A, const float* __restrict__ W,
              const float* __restrict__ bias, float* __restrict__ C,
              int N, int K, int ldw, int woff)
{
    __shared__ float As[64][33];
    __shared__ float Ws[64][33];
    const int tid = threadIdx.x;
    const int tx = tid & 15, ty = tid >> 4;
    const int m0 = blockIdx.x * 64, n0 = blockIdx.y * 64;
    const int kc = tid & 31;
    const int r0 = tid >> 5;
    float acc[4][4] = {};
    for (int k0 = 0; k0 < K; k0 += 32) {
        #pragma unroll
        for (int i = 0; i < 8; ++i) {
            int row = r0 + i * 8;
            As[row][kc] = A[(m0 + row) * K + k0 + kc];
            int n = n0 + row;
            Ws[row][kc] = (n < N) ? W[(long)n * ldw + woff + k0 + kc] : 0.f;
        }
        __syncthreads();
        #pragma unroll
        for (int kk = 0; kk < 32; ++kk) {
            float a[4], w[4];
            #pragma unroll
            for (int i = 0; i < 4; ++i) a[i] = As[ty * 4 + i][kk];
            #pragma unroll
            for (int j = 0; j < 4; ++j) w[j] = Ws[tx * 4 + j][kk];
            #pragma unroll
            for (int i = 0; i < 4; ++i)
                #pragma unroll
                for (int j = 0; j < 4; ++j) acc[i][j] += a[i] * w[j];
        }
        __syncthreads();
    }
    #pragma unroll
    for (int i = 0; i < 4; ++i) {
        int m = m0 + ty * 4 + i;
        #pragma unroll
        for (int j = 0; j < 4; ++j) {
            int n = n0 + tx * 4 + j;
            if (n < N) C[m * N + n] = acc[i][j] + (bias ? bias[n] : 0.f);
        }
    }
}

// ---------------- attention: one block per (row n, head h). 8 heads, HEAD_D=32.
__global__ __launch_bounds__(256)
void attn_kernel(const float* __restrict__ qkv, float* __restrict__ out)
{
    const int n = blockIdx.x;
    const int h = blockIdx.y;
    const int tid = threadIdx.x;
    const int lane = tid & 63;
    const int wid = tid >> 6;

    __shared__ float qs[32];
    __shared__ float p[384];
    __shared__ float red[8];
    __shared__ float pv[8][32];

    if (tid < 32) qs[tid] = qkv[n * 768 + h * 32 + tid] * 0.17677669529663687f;
    __syncthreads();

    float lmax = -1e30f;
    for (int m = tid; m < 384; m += 256) {
        const float4* kr = (const float4*)(qkv + m * 768 + 256 + h * 32);
        float s = 0.f;
        #pragma unroll
        for (int d = 0; d < 8; ++d) {
            float4 kv = kr[d];
            s += qs[d*4+0]*kv.x + qs[d*4+1]*kv.y + qs[d*4+2]*kv.z + qs[d*4+3]*kv.w;
        }
        p[m] = s;
        lmax = fmaxf(lmax, s);
    }
    #pragma unroll
    for (int off = 32; off >= 1; off >>= 1) lmax = fmaxf(lmax, __shfl_xor(lmax, off));
    if (lane == 0) red[wid] = lmax;
    __syncthreads();
    const float gmax = fmaxf(fmaxf(red[0], red[1]), fmaxf(red[2], red[3]));

    float lsum = 0.f;
    for (int m = tid; m < 384; m += 256) {
        float e = __expf(p[m] - gmax);
        p[m] = e;
        lsum += e;
    }
    #pragma unroll
    for (int off = 32; off >= 1; off >>= 1) lsum += __shfl_xor(lsum, off);
    if (lane == 0) red[4 + wid] = lsum;
    __syncthreads();
    const float inv = 1.f / (red[4] + red[5] + red[6] + red[7]);

    const int d = tid & 31;
    const int g = tid >> 5;
    float acc = 0.f;
    for (int m = g * 48; m < g * 48 + 48; ++m)
        acc += p[m] * qkv[m * 768 + 512 + h * 32 + d];
    pv[g][d] = acc;
    __syncthreads();
    if (tid < 32) {
        float o = 0.f;
        #pragma unroll
        for (int gg = 0; gg < 8; ++gg) o += pv[gg][tid];
        out[n * 256 + h * 32 + tid] = o * inv;
    }
}

// ---------------- fused tail: hA / hBv / node(+scatter) GEMMs + fci_w2 permute->bf16.
// grid (6, 11), 256 threads. y<4: hA, y<8: hBv, y<10: node->scatter, y==10: w2 permute.
// w2p layout (uint4 units): W2P[((ph*8+kk)*400 + n)*4 + kg] = bf16x8 of
//   fci_w2[(ph*400+n)*256 + kk*32 + kg*8 .. +8]
__global__ __launch_bounds__(256)
void fused_tail(const float* __restrict__ h2,
                const float* __restrict__ fci_w1, const float* __restrict__ fci_b1,
                const float* __restrict__ fcn_w,  const float* __restrict__ fcn_b,
                const float* __restrict__ fci_w2,
                float* __restrict__ hA, float* __restrict__ hBv,
                uint4* __restrict__ w2p, float* __restrict__ out)
{
    const int y = blockIdx.y;
    const int tid = threadIdx.x;
    if (y == 10) {
        for (int c = blockIdx.x * 256 + tid; c < 25600; c += 1536) {
            const int n_g = c >> 5, e = c & 31;
            const int kk = e >> 2, kg = e & 3;
            const int ph = (n_g >= 400) ? 1 : 0;
            const int n = n_g - ph * 400;
            const float4* s = (const float4*)(fci_w2 + n_g * 256 + kk * 32 + kg * 8);
            const float4 x0 = s[0], x1 = s[1];
            uint4 pk;
            pk.x = f2bf(x0.x) | (f2bf(x0.y) << 16);
            pk.y = f2bf(x0.z) | (f2bf(x0.w) << 16);
            pk.z = f2bf(x1.x) | (f2bf(x1.y) << 16);
            pk.w = f2bf(x1.z) | (f2bf(x1.w) << 16);
            w2p[((ph * 8 + kk) * 400 + n) * 4 + kg] = pk;
        }
        return;
    }
    const float* W    = (y < 8) ? fci_w1 : fcn_w;
    const float* bias = (y < 4) ? fci_b1 : ((y < 8) ? nullptr : fcn_b);
    const int ldw  = (y < 8) ? 512 : 256;
    const int woff = (y >= 4 && y < 8) ? 256 : 0;
    const int n0   = (y < 4) ? y * 64 : ((y < 8) ? (y - 4) * 64 : (y - 8) * 64);
    const int NN   = (y < 8) ? 256 : 80;

    __shared__ float As[64][33];
    __shared__ float Ws[64][33];
    const int tx = tid & 15, ty = tid >> 4;
    const int m0 = blockIdx.x * 64;
    const int kc = tid & 31;
    const int r0 = tid >> 5;
    float acc[4][4] = {};
    for (int k0 = 0; k0 < 256; k0 += 32) {
        #pragma unroll
        for (int i = 0; i < 8; ++i) {
            int row = r0 + i * 8;
            As[row][kc] = h2[(m0 + row) * 256 + k0 + kc];
            int n = n0 + row;
            Ws[row][kc] = (n < NN) ? W[(long)n * ldw + woff + k0 + kc] : 0.f;
        }
        __syncthreads();
        #pragma unroll
        for (int kk = 0; kk < 32; ++kk) {
            float a[4], w[4];
            #pragma unroll
            for (int i = 0; i < 4; ++i) a[i] = As[ty * 4 + i][kk];
            #pragma unroll
            for (int j = 0; j < 4; ++j) w[j] = Ws[tx * 4 + j][kk];
            #pragma unroll
            for (int i = 0; i < 4; ++i)
                #pragma unroll
                for (int j = 0; j < 4; ++j) acc[i][j] += a[i] * w[j];
        }
        __syncthreads();
    }
    if (y < 8) {
        float* C = (y < 4) ? hA : hBv;
        #pragma unroll
        for (int i = 0; i < 4; ++i) {
            int m = m0 + ty * 4 + i;
            #pragma unroll
            for (int j = 0; j < 4; ++j) {
                int n = n0 + tx * 4 + j;
                C[m * 256 + n] = acc[i][j] + (bias ? bias[n] : 0.f);
            }
        }
    } else {
        #pragma unroll
        for (int i = 0; i < 4; ++i) {
            int m = m0 + ty * 4 + i;
            #pragma unroll
            for (int j = 0; j < 4; ++j) {
                int c = n0 + tx * 4 + j;
                if (c < 80) {
                    float v = acc[i][j] + fcn_b[c];
                    if (c < 64)      out[117964800 + m * 64 + c] = v;
                    else if (c < 72) out[117989376 + m * 8 + (c - 64)] = v;
                    else             out[117992448 + m * 8 + (c - 72)] = v;
                }
            }
        }
    }
}

// ---------------- gen_kq v3: linear-store design.
// Block = 128 rows x (phase 0: K cols 0..400, phase 1: Q cols 0..400).
// 640 threads = 10 waves (2M x 5N). acc 4x5 f32x4 (bias-initialized).
// A: tanh'd bf16 image in LDS (64KB, built once). B: per-32k-chunk 25.6KB LDS
// staged from pre-permuted w2p via reg double-buffer. Epilogue: acc -> Cs
// (51.2KB LDS) -> flat contiguous global stores (wave writes 1KB runs).
__global__ __launch_bounds__(640, 3)
void gen_kq(const float* __restrict__ hA, const float* __restrict__ hB,
            const uint4* __restrict__ w2p, const float* __restrict__ b2,
            float* __restrict__ outK, float* __restrict__ outQ)
{
    __shared__ unsigned char Asm[128 * 512];   // 64 KB  A image, swizzled
    __shared__ unsigned char Bsm[400 * 64];    // 25.6 KB B k-chunk [row][64B]
    __shared__ unsigned char Csm[32 * 1600];   // 51.2 KB epilogue tile [32][400 f32]

    const int tid  = threadIdx.x;
    const int lane = tid & 63;
    const int wid  = tid >> 6;          // 0..9
    const int wm   = wid / 5;           // 0..1  (M half)
    const int wn   = wid % 5;           // 0..4  (N fifth)
    const int lr   = lane & 15;
    const int kg   = lane >> 4;

    const int m0  = blockIdx.x * 128;
    const int ai  = m0 / 384;           // constant per block (384 = 3*128)
    const int bj0 = m0 - ai * 384;

    // ---- A image: tanh(hA[bj0+row] + hB[ai]) -> bf16, 4096 cells of 16B
    for (int c = tid; c < 4096; c += 640) {
        const int row = c >> 5;
        const int e   = c & 31;
        const int kkc = e >> 2, kgc = e & 3;
        const int ke  = kkc * 32 + kgc * 8;
        const float4 a0 = *(const float4*)(hA + (bj0 + row) * 256 + ke);
        const float4 a1 = *(const float4*)(hA + (bj0 + row) * 256 + ke + 4);
        const float4 b0 = *(const float4*)(hB + ai * 256 + ke);
        const float4 b1 = *(const float4*)(hB + ai * 256 + ke + 4);
        uint4 pk;
        pk.x = f2bf(fast_tanh(a0.x + b0.x)) | (f2bf(fast_tanh(a0.y + b0.y)) << 16);
        pk.y = f2bf(fast_tanh(a0.z + b0.z)) | (f2bf(fast_tanh(a0.w + b0.w)) << 16);
        pk.z = f2bf(fast_tanh(a1.x + b1.x)) | (f2bf(fast_tanh(a1.y + b1.y)) << 16);
        pk.w = f2bf(fast_tanh(a1.z + b1.z)) | (f2bf(fast_tanh(a1.w + b1.w)) << 16);
        *(uint4*)(Asm + row * 512 + ((kkc * 64 + kgc * 16) ^ ((row & 7) << 4))) = pk;
    }

    // ---- B reg prefetch helpers (1600 uint4 per chunk; threads 0..319 take a 3rd)
    uint4 brA0, brA1, brA2, brB0, brB1, brB2;
    const int f2v = 1280 + tid;         // valid if tid < 320 (waves 0..4, uniform)

    #define LOADB(r0_, r1_, r2_, ph_, kk_) do {                                   \
        const uint4* _s = w2p + ((ph_) * 8 + (kk_)) * 1600;                       \
        r0_ = _s[tid];  r1_ = _s[640 + tid];                                      \
        if (tid < 320) r2_ = _s[f2v];                                             \
    } while (0)

    #define STOREB(r0_, r1_, r2_) do {                                            \
        *(uint4*)(Bsm + tid * 16) = r0_;                                          \
        *(uint4*)(Bsm + (640 + tid) * 16) = r1_;                                  \
        if (tid < 320) *(uint4*)(Bsm + f2v * 16) = r2_;                           \
    } while (0)

    LOADB(brA0, brA1, brA2, 0, 0);
    __syncthreads();    // A image complete

    #pragma unroll
    for (int ph = 0; ph < 2; ++ph) {
        // ---- acc init = bias (broadcast across rows)
        f32x4 acc[4][5];
        #pragma unroll
        for (int j = 0; j < 5; ++j) {
            const float4 bb = *(const float4*)(b2 + ph * 400 + wn * 80 + j * 16 + kg * 4);
            #pragma unroll
            for (int i = 0; i < 4; ++i)
                acc[i][j] = (f32x4){bb.x, bb.y, bb.z, bb.w};
        }

        #define COMPUTE(kk_) do {                                                 \
            bf16x8 af_[4], bf_[5];                                                \
            _Pragma("unroll")                                                     \
            for (int i = 0; i < 4; ++i) {                                         \
                const int row = wm * 64 + i * 16 + lr;                            \
                af_[i] = *(const bf16x8*)(Asm + row * 512 +                       \
                          (((kk_) * 64 + kg * 16) ^ ((row & 7) << 4)));           \
            }                                                                     \
            _Pragma("unroll")                                                     \
            for (int j = 0; j < 5; ++j) {                                         \
                const int rb = wn * 80 + j * 16 + lr;                             \
                bf_[j] = *(const bf16x8*)(Bsm + rb * 64 + kg * 16);               \
            }                                                                     \
            _Pragma("unroll")                                                     \
            for (int i = 0; i < 4; ++i)                                           \
                _Pragma("unroll")                                                 \
                for (int j = 0; j < 5; ++j)                                       \
                    acc[i][j] = __builtin_amdgcn_mfma_f32_16x16x32_bf16(          \
                        bf_[j], af_[i], acc[i][j], 0, 0, 0);                      \
        } while (0)

        #pragma unroll
        for (int kk2 = 0; kk2 < 4; ++kk2) {
            const int kk = kk2 * 2;
            // even step
            STOREB(brA0, brA1, brA2);
            LOADB(brB0, brB1, brB2, ph, kk + 1);
            __syncthreads();            // Bsm ready
            COMPUTE(kk);
            __syncthreads();            // Bsm free
            // odd step
            STOREB(brB0, brB1, brB2);
            if (kk + 2 < 8) { LOADB(brA0, brA1, brA2, ph, kk + 2); }
            else if (ph == 0) { LOADB(brA0, brA1, brA2, 1, 0); }
            __syncthreads();            // Bsm ready
            COMPUTE(kk + 1);
            __syncthreads();            // Bsm free
        }

        // ---- epilogue: 4 passes of 32 rows through Cs, flat contiguous stores
        float* gob = ph ? outQ : outK;
        #pragma unroll
        for (int p = 0; p < 4; ++p) {
            if (wm == (p >> 1)) {
                #pragma unroll
                for (int i2 = 0; i2 < 2; ++i2) {
                    const int i = 2 * (p & 1) + i2;
                    const int crow = i2 * 16 + lr;
                    #pragma unroll
                    for (int j = 0; j < 5; ++j) {
                        float4 v;
                        v.x = acc[i][j][0]; v.y = acc[i][j][1];
                        v.z = acc[i][j][2]; v.w = acc[i][j][3];
                        *(float4*)(Csm + crow * 1600 + (wn * 80 + j * 16 + kg * 4) * 4) = v;
                    }
                }
            }
            __syncthreads();            // Cs ready
            {
                float* gb = gob + (size_t)m0 * 400 + p * 12800;
                #pragma unroll
                for (int q = 0; q < 5; ++q) {
                    const int f = q * 640 + tid;     // 0..3199, global = gb + f*4
                    const float4 v = *(const float4*)(Csm + f * 16);
                    *(float4*)(gb + f * 4) = v;
                }
            }
            __syncthreads();            // Cs free (for next pass)
        }
    }
}

extern "C" void kernel_launch(void* const* d_in, const int* in_sizes, int n_in,
                              void* d_out, int out_size, void* d_ws, size_t ws_size,
                              hipStream_t stream)
{
    (void)in_sizes; (void)n_in; (void)out_size; (void)ws_size;

    const float* h      = (const float*)d_in[0];
    const float* fc_w   = (const float*)d_in[1];
    const float* fc_b   = (const float*)d_in[2];
    const float* inp_w  = (const float*)d_in[3];
    const float* inp_b  = (const float*)d_in[4];
    const float* outp_w = (const float*)d_in[5];
    const float* outp_b = (const float*)d_in[6];
    const float* fci_w1 = (const float*)d_in[7];
    const float* fci_b1 = (const float*)d_in[8];
    const float* fci_w2 = (const float*)d_in[9];
    const float* fci_b2 = (const float*)d_in[10];
    const float* fcn_w  = (const float*)d_in[11];
    const float* fcn_b  = (const float*)d_in[12];

    float* out  = (float*)d_out;
    float* outK = out;
    float* outQ = out + 58982400;   // 384*384*400

    float* ws   = (float*)d_ws;
    float* h1   = ws;                    // 384*256
    float* qkv  = h1   + 384 * 256;      // 384*768
    float* attn = qkv  + 384 * 768;      // 384*256
    float* h2   = attn + 384 * 256;      // 384*256
    float* hA   = h2   + 384 * 256;      // 384*256  (b1 folded in)
    float* hBv  = hA   + 384 * 256;      // 384*256
    float* node = hBv  + 384 * 256;      // 384*80 (reserved)
    uint4* w2p  = (uint4*)(node + 384 * 80); // 800*256 bf16, permuted [2][8][400][4x uint4]

    sgemm_bt<<<dim3(6, 4),  256, 0, stream>>>(h,    fc_w,   fc_b,   h1,   256, 128, 128, 0);
    sgemm_bt<<<dim3(6, 12), 256, 0, stream>>>(h1,   inp_w,  inp_b,  qkv,  768, 256, 256, 0);
    attn_kernel<<<dim3(384, 8), 256, 0, stream>>>(qkv, attn);
    sgemm_bt<<<dim3(6, 4),  256, 0, stream>>>(attn, outp_w, outp_b, h2,   256, 256, 256, 0);
    fused_tail<<<dim3(6, 11), 256, 0, stream>>>(h2, fci_w1, fci_b1, fcn_w, fcn_b, fci_w2,
                                                hA, hBv, w2p, out);
    gen_kq<<<dim3(1152), 640, 0, stream>>>(hA, hBv, w2p, fci_b2, outK, outQ);
}

// Round 4
// 255.380 us; speedup vs baseline: 2.4271x; 1.6247x over previous
//
#include <hip/hip_runtime.h>
#include <hip/hip_bf16.h>

typedef __attribute__((ext_vector_type(8))) short bf16x8;
typedef __attribute__((ext_vector_type(4))) float f32x4;

static __device__ __forceinline__ unsigned int f2bf(float f) {
    unsigned int u = __float_as_uint(f);
    u = u + 0x7FFFu + ((u >> 16) & 1u);   // RNE; inputs are finite
    return (u >> 16);
}

static __device__ __forceinline__ float fast_tanh(float x) {
    x = fminf(fmaxf(x, -10.f), 10.f);
    float e = __expf(2.f * x);
    return __fdividef(e - 1.f, e + 1.f);
}

// LDS-only barrier: global stores are NOT drained (vmcnt untouched).
#define LGKM_BAR() do {                                      \
    asm volatile("s_waitcnt lgkmcnt(0)" ::: "memory");       \
    __builtin_amdgcn_s_barrier();                            \
} while (0)

// ---------------- prep: weight transposes into ws + fci_w2 permute->bf16
__global__ __launch_bounds__(256)
void prep(const float* __restrict__ fc_w, const float* __restrict__ inp_w,
          const float* __restrict__ outp_w, const float* __restrict__ fci_w1,
          const float* __restrict__ fcn_w, const float* __restrict__ fci_w2,
          float* __restrict__ fcwT, float* __restrict__ inpT,
          float* __restrict__ outpT, float* __restrict__ waT,
          float* __restrict__ wbT, float* __restrict__ fcnT,
          uint4* __restrict__ w2p)
{
    const int idx0 = blockIdx.x * 256 + threadIdx.x;
    const int stride = 64 * 256;
    switch (blockIdx.y) {
    case 0:
        for (int c = idx0; c < 32768; c += stride) {
            int k = c >> 8, n = c & 255;
            fcwT[c] = fc_w[n * 128 + k];
        }
        break;
    case 1:
        for (int c = idx0; c < 196608; c += stride) {
            int k = c / 768, n = c - k * 768;
            inpT[c] = inp_w[n * 256 + k];
        }
        break;
    case 2:
        for (int c = idx0; c < 65536; c += stride) {
            int k = c >> 8, n = c & 255;
            outpT[c] = outp_w[n * 256 + k];
        }
        break;
    case 3:
        for (int c = idx0; c < 65536; c += stride) {
            int k = c >> 8, n = c & 255;
            waT[c] = fci_w1[n * 512 + k];
        }
        break;
    case 4:
        for (int c = idx0; c < 65536; c += stride) {
            int k = c >> 8, n = c & 255;
            wbT[c] = fci_w1[n * 512 + 256 + k];
        }
        break;
    case 5:
        for (int c = idx0; c < 20480; c += stride) {
            int k = c / 80, n = c - k * 80;
            fcnT[c] = fcn_w[n * 256 + k];
        }
        break;
    default:
        for (int c = idx0; c < 25600; c += stride) {
            const int n_g = c >> 5, e = c & 31;
            const int kk = e >> 2, kg = e & 3;
            const int ph = (n_g >= 400) ? 1 : 0;
            const int n = n_g - ph * 400;
            const float4* s = (const float4*)(fci_w2 + n_g * 256 + kk * 32 + kg * 8);
            const float4 x0 = s[0], x1 = s[1];
            uint4 pk;
            pk.x = f2bf(x0.x) | (f2bf(x0.y) << 16);
            pk.y = f2bf(x0.z) | (f2bf(x0.w) << 16);
            pk.z = f2bf(x1.x) | (f2bf(x1.y) << 16);
            pk.w = f2bf(x1.z) | (f2bf(x1.w) << 16);
            w2p[((ph * 8 + kk) * 400 + n) * 4 + kg] = pk;
        }
        break;
    }
}

// ---------------- k1: per-row h1 -> qkv (384 blocks x 256 thr)
__global__ __launch_bounds__(256)
void k1_rows(const float* __restrict__ h, const float* __restrict__ fc_b,
             const float* __restrict__ inp_b, const float* __restrict__ fcwT,
             const float* __restrict__ inpT, float* __restrict__ qkv)
{
    __shared__ float hrow[128];
    __shared__ float h1row[256];
    const int i = blockIdx.x, tid = threadIdx.x;
    if (tid < 128) hrow[tid] = h[i * 128 + tid];
    __syncthreads();
    float acc = fc_b[tid];
    #pragma unroll 8
    for (int k = 0; k < 128; ++k) acc += hrow[k] * fcwT[k * 256 + tid];
    h1row[tid] = acc;
    __syncthreads();
    float a0 = inp_b[tid], a1 = inp_b[tid + 256], a2 = inp_b[tid + 512];
    #pragma unroll 8
    for (int k = 0; k < 256; ++k) {
        const float f = h1row[k];
        a0 += f * inpT[k * 768 + tid];
        a1 += f * inpT[k * 768 + tid + 256];
        a2 += f * inpT[k * 768 + tid + 512];
    }
    qkv[i * 768 + tid] = a0;
    qkv[i * 768 + tid + 256] = a1;
    qkv[i * 768 + tid + 512] = a2;
}

// ---------------- attention: one block per (row n, head h). 8 heads, HEAD_D=32.
__global__ __launch_bounds__(256)
void attn_kernel(const float* __restrict__ qkv, float* __restrict__ out)
{
    const int n = blockIdx.x;
    const int h = blockIdx.y;
    const int tid = threadIdx.x;
    const int lane = tid & 63;
    const int wid = tid >> 6;

    __shared__ float qs[32];
    __shared__ float p[384];
    __shared__ float red[8];
    __shared__ float pv[8][32];

    if (tid < 32) qs[tid] = qkv[n * 768 + h * 32 + tid] * 0.17677669529663687f;
    __syncthreads();

    float lmax = -1e30f;
    for (int m = tid; m < 384; m += 256) {
        const float4* kr = (const float4*)(qkv + m * 768 + 256 + h * 32);
        float s = 0.f;
        #pragma unroll
        for (int d = 0; d < 8; ++d) {
            float4 kv = kr[d];
            s += qs[d*4+0]*kv.x + qs[d*4+1]*kv.y + qs[d*4+2]*kv.z + qs[d*4+3]*kv.w;
        }
        p[m] = s;
        lmax = fmaxf(lmax, s);
    }
    #pragma unroll
    for (int off = 32; off >= 1; off >>= 1) lmax = fmaxf(lmax, __shfl_xor(lmax, off));
    if (lane == 0) red[wid] = lmax;
    __syncthreads();
    const float gmax = fmaxf(fmaxf(red[0], red[1]), fmaxf(red[2], red[3]));

    float lsum = 0.f;
    for (int m = tid; m < 384; m += 256) {
        float e = __expf(p[m] - gmax);
        p[m] = e;
        lsum += e;
    }
    #pragma unroll
    for (int off = 32; off >= 1; off >>= 1) lsum += __shfl_xor(lsum, off);
    if (lane == 0) red[4 + wid] = lsum;
    __syncthreads();
    const float inv = 1.f / (red[4] + red[5] + red[6] + red[7]);

    const int d = tid & 31;
    const int g = tid >> 5;
    float acc = 0.f;
    for (int m = g * 48; m < g * 48 + 48; ++m)
        acc += p[m] * qkv[m * 768 + 512 + h * 32 + d];
    pv[g][d] = acc;
    __syncthreads();
    if (tid < 32) {
        float o = 0.f;
        #pragma unroll
        for (int gg = 0; gg < 8; ++gg) o += pv[gg][tid];
        out[n * 256 + h * 32 + tid] = o * inv;
    }
}

// ---------------- k3: per-row h2 -> hA/hB/node(+scatter) (384 blocks x 256 thr)
__global__ __launch_bounds__(256)
void k3_rows(const float* __restrict__ attnO, const float* __restrict__ outp_b,
             const float* __restrict__ fci_b1, const float* __restrict__ fcn_b,
             const float* __restrict__ outpT, const float* __restrict__ waT,
             const float* __restrict__ wbT, const float* __restrict__ fcnT,
             float* __restrict__ hA, float* __restrict__ hB, float* __restrict__ out)
{
    __shared__ float arow[256];
    __shared__ float h2row[256];
    const int i = blockIdx.x, tid = threadIdx.x;
    arow[tid] = attnO[i * 256 + tid];
    __syncthreads();
    float acc = outp_b[tid];
    #pragma unroll 8
    for (int k = 0; k < 256; ++k) acc += arow[k] * outpT[k * 256 + tid];
    h2row[tid] = acc;
    __syncthreads();
    float aA = fci_b1[tid], aB = 0.f;
    #pragma unroll 8
    for (int k = 0; k < 256; ++k) {
        const float f = h2row[k];
        aA += f * waT[k * 256 + tid];
        aB += f * wbT[k * 256 + tid];
    }
    hA[i * 256 + tid] = aA;
    hB[i * 256 + tid] = aB;
    if (tid < 80) {
        float aN = fcn_b[tid];
        #pragma unroll 8
        for (int k = 0; k < 256; ++k) aN += h2row[k] * fcnT[k * 80 + tid];
        if (tid < 64)      out[117964800 + i * 64 + tid] = aN;
        else if (tid < 72) out[117989376 + i * 8 + (tid - 64)] = aN;
        else               out[117992448 + i * 8 + (tid - 72)] = aN;
    }
}

// ---------------- gen_kq v4: barrier-light, store-overlapped.
// BM=96 rows/block (grid 1536 = 6/CU exactly). A: tanh'd bf16 image in LDS (48KB),
// built once. B: fragments read DIRECTLY from L2-resident w2p (contiguous 1KB/wave)
// -> zero barriers in the K-loop; 10 waves run independently. Epilogue: acc -> Csm
// (51.2KB) -> full-line contiguous stores, with LDS-only barriers (lgkmcnt, no vmcnt
// drain) so stores stay in flight and drain under subsequent compute.
__global__ __launch_bounds__(640, 1)
void gen_kq(const float* __restrict__ hA, const float* __restrict__ hB,
            const uint4* __restrict__ w2p, const float* __restrict__ b2,
            float* __restrict__ outK, float* __restrict__ outQ)
{
    __shared__ unsigned char Aim[96 * 512];    // 48 KB  A image, XOR-swizzled
    __shared__ unsigned char Csm[32 * 1600];   // 51.2 KB epilogue tile [32][400 f32]

    const int tid  = threadIdx.x;
    const int lane = tid & 63;
    const int wid  = tid >> 6;          // 0..9
    const int wm   = wid / 5;           // 0..1  (48-row half)
    const int wn   = wid % 5;           // 0..4  (80-col fifth)
    const int lr   = lane & 15;
    const int kg   = lane >> 4;

    const int bid = blockIdx.x;
    const int m0  = bid * 96;
    const int ai  = bid >> 2;           // exact: 384 = 4*96
    const int bj0 = (bid & 3) * 96;

    // ---- A image: tanh(hA[bj0+row] + hB[ai]) -> bf16, 3072 cells of 16B
    for (int c = tid; c < 3072; c += 640) {
        const int row = c >> 5;
        const int e   = c & 31;
        const int ke  = e * 8;
        const float4 a0 = *(const float4*)(hA + (bj0 + row) * 256 + ke);
        const float4 a1 = *(const float4*)(hA + (bj0 + row) * 256 + ke + 4);
        const float4 b0 = *(const float4*)(hB + ai * 256 + ke);
        const float4 b1 = *(const float4*)(hB + ai * 256 + ke + 4);
        uint4 pk;
        pk.x = f2bf(fast_tanh(a0.x + b0.x)) | (f2bf(fast_tanh(a0.y + b0.y)) << 16);
        pk.y = f2bf(fast_tanh(a0.z + b0.z)) | (f2bf(fast_tanh(a0.w + b0.w)) << 16);
        pk.z = f2bf(fast_tanh(a1.x + b1.x)) | (f2bf(fast_tanh(a1.y + b1.y)) << 16);
        pk.w = f2bf(fast_tanh(a1.z + b1.z)) | (f2bf(fast_tanh(a1.w + b1.w)) << 16);
        *(uint4*)(Aim + row * 512 + ((e * 16) ^ ((row & 7) << 4))) = pk;
    }
    LGKM_BAR();

    #pragma unroll
    for (int ph = 0; ph < 2; ++ph) {
        // ---- acc init = bias (cols n = wn*80 + j*16 + kg*4 + reg)
        f32x4 acc[3][5];
        #pragma unroll
        for (int j = 0; j < 5; ++j) {
            const float4 bb = *(const float4*)(b2 + ph * 400 + wn * 80 + j * 16 + kg * 4);
            #pragma unroll
            for (int i = 0; i < 3; ++i)
                acc[i][j] = (f32x4){bb.x, bb.y, bb.z, bb.w};
        }

        // ---- K-loop: no barriers. A from LDS, B direct from L2.
        #pragma unroll
        for (int kk = 0; kk < 8; ++kk) {
            bf16x8 af_[3], bf_[5];
            #pragma unroll
            for (int i = 0; i < 3; ++i) {
                const int row = wm * 48 + i * 16 + lr;
                af_[i] = *(const bf16x8*)(Aim + row * 512 +
                          ((kk * 64 + kg * 16) ^ ((row & 7) << 4)));
            }
            const uint4* wb = w2p + (ph * 8 + kk) * 1600;
            #pragma unroll
            for (int j = 0; j < 5; ++j)
                bf_[j] = *(const bf16x8*)(wb + (wn * 80 + j * 16 + lr) * 4 + kg);
            #pragma unroll
            for (int i = 0; i < 3; ++i)
                #pragma unroll
                for (int j = 0; j < 5; ++j)
                    acc[i][j] = __builtin_amdgcn_mfma_f32_16x16x32_bf16(
                        bf_[j], af_[i], acc[i][j], 0, 0, 0);
        }

        // ---- epilogue: 3 passes of 32 rows through Csm; LDS-only barriers.
        float* gob = ph ? outQ : outK;
        #pragma unroll
        for (int p = 0; p < 3; ++p) {
            #pragma unroll
            for (int i = 0; i < 3; ++i) {
                const int r = wm * 3 + i;          // fragment's 16-row index (0..5)
                if (r == 2 * p || r == 2 * p + 1) {
                    const int crow = (r - 2 * p) * 16 + lr;
                    #pragma unroll
                    for (int j = 0; j < 5; ++j) {
                        float4 v;
                        v.x = acc[i][j][0]; v.y = acc[i][j][1];
                        v.z = acc[i][j][2]; v.w = acc[i][j][3];
                        *(float4*)(Csm + crow * 1600 + (wn * 80 + j * 16 + kg * 4) * 4) = v;
                    }
                }
            }
            LGKM_BAR();                            // Csm ready (ds only)
            {
                float* gb = gob + (size_t)m0 * 400 + p * 12800;
                #pragma unroll
                for (int q = 0; q < 5; ++q) {
                    const int f = q * 640 + tid;   // 0..3199
                    const float4 v = *(const float4*)(Csm + f * 16);
                    *(float4*)(gb + f * 4) = v;
                }
            }
            LGKM_BAR();                            // Csm free (reads done; stores fly on)
        }
    }
}

extern "C" void kernel_launch(void* const* d_in, const int* in_sizes, int n_in,
                              void* d_out, int out_size, void* d_ws, size_t ws_size,
                              hipStream_t stream)
{
    (void)in_sizes; (void)n_in; (void)out_size; (void)ws_size;

    const float* h      = (const float*)d_in[0];
    const float* fc_w   = (const float*)d_in[1];
    const float* fc_b   = (const float*)d_in[2];
    const float* inp_w  = (const float*)d_in[3];
    const float* inp_b  = (const float*)d_in[4];
    const float* outp_w = (const float*)d_in[5];
    const float* outp_b = (const float*)d_in[6];
    const float* fci_w1 = (const float*)d_in[7];
    const float* fci_b1 = (const float*)d_in[8];
    const float* fci_w2 = (const float*)d_in[9];
    const float* fci_b2 = (const float*)d_in[10];
    const float* fcn_w  = (const float*)d_in[11];
    const float* fcn_b  = (const float*)d_in[12];

    float* out  = (float*)d_out;
    float* outK = out;
    float* outQ = out + 58982400;   // 384*384*400

    float* ws    = (float*)d_ws;
    float* qkv   = ws;                       // 294912
    float* attnO = qkv   + 294912;           // 98304
    float* hA    = attnO + 98304;            // 98304 (b1 folded in)
    float* hBv   = hA    + 98304;            // 98304
    float* fcwT  = hBv   + 98304;            // 32768
    float* inpT  = fcwT  + 32768;            // 196608
    float* outpT = inpT  + 196608;           // 65536
    float* waT   = outpT + 65536;            // 65536
    float* wbT   = waT   + 65536;            // 65536
    float* fcnT  = wbT   + 65536;            // 20480
    uint4* w2p   = (uint4*)(fcnT + 20480);   // 409600 B, 16B-aligned

    prep<<<dim3(64, 7), 256, 0, stream>>>(fc_w, inp_w, outp_w, fci_w1, fcn_w, fci_w2,
                                          fcwT, inpT, outpT, waT, wbT, fcnT, w2p);
    k1_rows<<<384, 256, 0, stream>>>(h, fc_b, inp_b, fcwT, inpT, qkv);
    attn_kernel<<<dim3(384, 8), 256, 0, stream>>>(qkv, attnO);
    k3_rows<<<384, 256, 0, stream>>>(attnO, outp_b, fci_b1, fcn_b, outpT, waT, wbT, fcnT,
                                     hA, hBv, out);
    gen_kq<<<dim3(1536), 640, 0, stream>>>(hA, hBv, w2p, fci_b2, outK, outQ);
}